// Round 2
// baseline (1074.989 us; speedup 1.0000x reference)
//
#include <hip/hip_runtime.h>

// Problem constants (AttnMLP): x [8,2048,2048] fp32 -> 16384 rows of D=2048.
#define D_EMBD 2048
#define MROWS  16384
#define TILE   128
#define BK     32

typedef _Float16 f16x8 __attribute__((ext_vector_type(8)));
typedef float    f32x4 __attribute__((ext_vector_type(4)));

__device__ __forceinline__ float fast_gelu(float x) {
    // 0.5*x*(1+tanh(sqrt(2/pi)*(x+0.044715 x^3))), tanh via exp (v_exp_f32)
    float u = 0.7978845608028654f * (x + 0.044715f * x * x * x);
    float e = __expf(2.0f * u);
    float t = 1.0f - 2.0f / (e + 1.0f);   // == tanh(u), saturates correctly at +/-inf
    return 0.5f * x * (1.0f + t);
}

// Async 16B global->LDS copy. LDS dest must be wave-uniform base + lane*16.
__device__ __forceinline__ void async16(const void* g, void* l) {
    __builtin_amdgcn_global_load_lds(
        (const __attribute__((address_space(1))) unsigned int*)g,
        (__attribute__((address_space(3))) unsigned int*)l, 16, 0, 0);
}

// ---------------------------------------------------------------------------
// W fp32 (N x K, i.e. torch (out,in)) -> fp16, one layer slice (2048x2048).
// grid 2048 x 256 threads, 8 elements/thread.
// ---------------------------------------------------------------------------
__global__ __launch_bounds__(256) void convert_w(const float* __restrict__ W,
                                                 _Float16* __restrict__ Wh) {
    const int i = blockIdx.x * 256 + threadIdx.x;   // float4-pair index
    const float4* src = (const float4*)W;
    float4 a = src[i * 2];
    float4 b = src[i * 2 + 1];
    f16x8 p;
    p[0] = (_Float16)a.x; p[1] = (_Float16)a.y; p[2] = (_Float16)a.z; p[3] = (_Float16)a.w;
    p[4] = (_Float16)b.x; p[5] = (_Float16)b.y; p[6] = (_Float16)b.z; p[7] = (_Float16)b.w;
    ((f16x8*)Wh)[i] = p;
}

// ---------------------------------------------------------------------------
// LayerNorm over D=2048, fp32 in -> fp16 out. One block (256 thr) per row,
// 8 elements/thread, float4 loads, wave-shuffle + LDS reduction.
// ---------------------------------------------------------------------------
__global__ __launch_bounds__(256) void ln_to_f16(const float* __restrict__ X,
                                                 const float* __restrict__ w,
                                                 const float* __restrict__ bln,
                                                 _Float16* __restrict__ H) {
    const int row = blockIdx.x;
    const int tid = threadIdx.x;
    const float* xr = X + (size_t)row * D_EMBD;

    float4 v0 = ((const float4*)xr)[tid * 2];
    float4 v1 = ((const float4*)xr)[tid * 2 + 1];

    float s  = ((v0.x + v0.y) + (v0.z + v0.w)) + ((v1.x + v1.y) + (v1.z + v1.w));
    float sq = v0.x * v0.x;
    sq = fmaf(v0.y, v0.y, sq); sq = fmaf(v0.z, v0.z, sq); sq = fmaf(v0.w, v0.w, sq);
    sq = fmaf(v1.x, v1.x, sq); sq = fmaf(v1.y, v1.y, sq);
    sq = fmaf(v1.z, v1.z, sq); sq = fmaf(v1.w, v1.w, sq);

    #pragma unroll
    for (int off = 32; off > 0; off >>= 1) {
        s  += __shfl_down(s, off);
        sq += __shfl_down(sq, off);
    }

    __shared__ float red[8];
    __shared__ float stats[2];
    const int wv = tid >> 6, ln = tid & 63;
    if (ln == 0) { red[wv] = s; red[4 + wv] = sq; }
    __syncthreads();
    if (tid == 0) {
        float ts = (red[0] + red[1]) + (red[2] + red[3]);
        float tq = (red[4] + red[5]) + (red[6] + red[7]);
        float mean = ts * (1.0f / D_EMBD);
        float var  = tq * (1.0f / D_EMBD) - mean * mean;
        stats[0] = mean;
        stats[1] = rsqrtf(var + 1e-5f);
    }
    __syncthreads();
    const float mean = stats[0], rstd = stats[1];

    float4 w0 = ((const float4*)w)[tid * 2],   w1 = ((const float4*)w)[tid * 2 + 1];
    float4 b0 = ((const float4*)bln)[tid * 2], b1 = ((const float4*)bln)[tid * 2 + 1];

    f16x8 p;
    p[0] = (_Float16)fmaf((v0.x - mean) * rstd, w0.x, b0.x);
    p[1] = (_Float16)fmaf((v0.y - mean) * rstd, w0.y, b0.y);
    p[2] = (_Float16)fmaf((v0.z - mean) * rstd, w0.z, b0.z);
    p[3] = (_Float16)fmaf((v0.w - mean) * rstd, w0.w, b0.w);
    p[4] = (_Float16)fmaf((v1.x - mean) * rstd, w1.x, b1.x);
    p[5] = (_Float16)fmaf((v1.y - mean) * rstd, w1.y, b1.y);
    p[6] = (_Float16)fmaf((v1.z - mean) * rstd, w1.z, b1.z);
    p[7] = (_Float16)fmaf((v1.w - mean) * rstd, w1.w, b1.w);
    ((f16x8*)(H + (size_t)row * D_EMBD))[tid] = p;
}

// ---------------------------------------------------------------------------
// C[m][n] = gelu( sum_k A[m][k]*B[n][k] + bias[n] )  (B given N x K = W (out,in))
// m97-style: 128x128 block tile, 4 waves in 2x2, each wave 4x4 of 16x16x32
// f16 MFMA tiles. global_load_lds width-16 staging into unpadded LDS.
// ---------------------------------------------------------------------------
__global__ __launch_bounds__(256) void gemm_bias_gelu(
    const _Float16* __restrict__ A,   // rows x K fp16 (LN output chunk)
    const _Float16* __restrict__ B,   // N x K fp16 (W layer)
    const float* __restrict__ bias,   // N fp32
    float* __restrict__ C)            // rows x N fp32
{
    constexpr int K = D_EMBD;
    constexpr int N = D_EMBD;
    __shared__ _Float16 As[TILE * BK];   // 8 KiB
    __shared__ _Float16 Bs[TILE * BK];   // 8 KiB

    const int tid  = threadIdx.x;
    const int m0   = blockIdx.x * TILE;
    const int n0   = blockIdx.y * TILE;
    const int wave = tid >> 6, lane = tid & 63;
    const int wr = wave >> 1, wc = wave & 1;   // 2x2 wave grid, 64x64 each
    const int q = lane >> 4, c16 = lane & 15;

    // Staging: tile is 128x32 f16 = 8192 B; 256 thr * 2 chunks * 16 B.
    // Chunk j covers elements [j*2048 + tid*8, +8): lane stride 16 B, wave-
    // uniform base per (j, wave) -> satisfies global_load_lds constraint.
    const int e0 = tid * 8;
    const int e1 = 2048 + tid * 8;
    const int r0 = e0 >> 5, cc0 = e0 & 31;
    const int r1 = e1 >> 5, cc1 = e1 & 31;

    const _Float16* Ab = A + (size_t)m0 * K;
    const _Float16* Bb = B + (size_t)n0 * K;

    f32x4 acc[4][4] = {};

    for (int k0 = 0; k0 < K; k0 += BK) {
        async16(Ab + (size_t)r0 * K + (k0 + cc0), &As[e0]);
        async16(Ab + (size_t)r1 * K + (k0 + cc1), &As[e1]);
        async16(Bb + (size_t)r0 * K + (k0 + cc0), &Bs[e0]);
        async16(Bb + (size_t)r1 * K + (k0 + cc1), &Bs[e1]);
        __syncthreads();   // drains vmcnt(0): LDS tiles ready

        f16x8 af[4], bf[4];
        #pragma unroll
        for (int i = 0; i < 4; i++)   // A frag: A[m = lane&15][k = q*8 + j]
            af[i] = *(const f16x8*)&As[(wr * 64 + i * 16 + c16) * BK + q * 8];
        #pragma unroll
        for (int i = 0; i < 4; i++)   // B frag: B[n = lane&15][k = q*8 + j]
            bf[i] = *(const f16x8*)&Bs[(wc * 64 + i * 16 + c16) * BK + q * 8];

        #pragma unroll
        for (int mi = 0; mi < 4; mi++)
            #pragma unroll
            for (int ni = 0; ni < 4; ni++)
                acc[mi][ni] = __builtin_amdgcn_mfma_f32_16x16x32_f16(
                    af[mi], bf[ni], acc[mi][ni], 0, 0, 0);
        __syncthreads();   // protect LDS before next stage
    }

    // Epilogue: C/D layout col = lane&15, row = q*4 + reg.
    #pragma unroll
    for (int ni = 0; ni < 4; ni++) {
        const int gcol = n0 + wc * 64 + ni * 16 + c16;
        const float bv = bias[gcol];
        #pragma unroll
        for (int mi = 0; mi < 4; mi++) {
            #pragma unroll
            for (int r = 0; r < 4; r++) {
                const int grow = m0 + wr * 64 + mi * 16 + q * 4 + r;
                C[(size_t)grow * N + gcol] = fast_gelu(acc[mi][ni][r] + bv);
            }
        }
    }
}

// ---------------------------------------------------------------------------
extern "C" void kernel_launch(void* const* d_in, const int* in_sizes, int n_in,
                              void* d_out, int out_size, void* d_ws, size_t ws_size,
                              hipStream_t stream) {
    const float* x    = (const float*)d_in[0];   // [8,2048,2048] fp32
    const float* W    = (const float*)d_in[1];   // [4,2048,2048] fp32 (out,in)
    const float* bias = (const float*)d_in[2];   // [4,2048]
    const float* lnw  = (const float*)d_in[3];   // [4,2048]
    const float* lnb  = (const float*)d_in[4];   // [4,2048]
    float* out = (float*)d_out;                  // [8,2048,2048] fp32

    // ws layout: Wh (one layer fp16, 8 MiB) | H (LN-output fp16, chunked).
    // CRITICAL: never exceed ws_size — overrunning d_ws corrupts neighboring
    // device allocations (the harness's pristine input copies), which poisons
    // every SUBSEQUENT call (round-1 failure mode). Size the H chunk to fit.
    const size_t whBytes = (size_t)D_EMBD * D_EMBD * sizeof(_Float16);  // 8 MiB
    _Float16* Wh = (_Float16*)d_ws;
    _Float16* H  = (_Float16*)((char*)d_ws + whBytes);

    const size_t rowBytes = (size_t)D_EMBD * sizeof(_Float16);  // 4 KiB
    long chRows = (ws_size > whBytes) ? (long)((ws_size - whBytes) / rowBytes) : 0;
    chRows = (chRows / TILE) * TILE;           // multiple of the GEMM tile
    if (chRows > MROWS) chRows = MROWS;        // 16384 % 128 == 0 -> even chunks
    if (chRows < TILE)  chRows = TILE;         // minimum viable (ws too small)

    for (int layer = 0; layer < 4; layer++) {
        convert_w<<<(D_EMBD * D_EMBD) / 2048, 256, 0, stream>>>(
            W + (size_t)layer * D_EMBD * D_EMBD, Wh);
        const float* Xin = (layer == 0) ? x : out;
        for (long m = 0; m < MROWS; m += chRows) {
            const long rows = (MROWS - m < chRows) ? (MROWS - m) : chRows;
            ln_to_f16<<<(int)rows, 256, 0, stream>>>(
                Xin + (size_t)m * D_EMBD, lnw + (size_t)layer * D_EMBD,
                lnb + (size_t)layer * D_EMBD, H);
            gemm_bias_gelu<<<dim3((int)(rows / TILE), D_EMBD / TILE), 256, 0, stream>>>(
                H, Wh, bias + (size_t)layer * D_EMBD, out + (size_t)m * D_EMBD);
        }
    }
}

// Round 4
// 1054.301 us; speedup vs baseline: 1.0196x; 1.0196x over previous
//
#include <hip/hip_runtime.h>

// Problem constants (AttnMLP): x [8,2048,2048] fp32 -> 16384 rows of D=2048.
#define D_EMBD 2048
#define MROWS  16384
#define TILE   128
#define BK     32

typedef _Float16 f16x8 __attribute__((ext_vector_type(8)));
typedef float    f32x4 __attribute__((ext_vector_type(4)));

__device__ __forceinline__ float fast_gelu(float x) {
    // 0.5*x*(1+tanh(sqrt(2/pi)*(x+0.044715 x^3))), tanh via exp (v_exp_f32)
    float u = 0.7978845608028654f * (x + 0.044715f * x * x * x);
    float e = __expf(2.0f * u);
    float t = 1.0f - 2.0f / (e + 1.0f);   // == tanh(u), saturates at +/-inf
    return 0.5f * x * (1.0f + t);
}

// Async 16B global->LDS copy. LDS dest must be wave-uniform base + lane*16.
__device__ __forceinline__ void async16(const void* g, void* l) {
    __builtin_amdgcn_global_load_lds(
        (const __attribute__((address_space(1))) unsigned int*)g,
        (__attribute__((address_space(3))) unsigned int*)l, 16, 0, 0);
}

// ---------------------------------------------------------------------------
// W fp32 (N x K = torch (out,in)) -> fp16, one layer slice (2048x2048).
// ---------------------------------------------------------------------------
__global__ __launch_bounds__(256) void convert_w(const float* __restrict__ W,
                                                 _Float16* __restrict__ Wh) {
    const int i = blockIdx.x * 256 + threadIdx.x;
    const float4* src = (const float4*)W;
    float4 a = src[i * 2];
    float4 b = src[i * 2 + 1];
    f16x8 p;
    p[0] = (_Float16)a.x; p[1] = (_Float16)a.y; p[2] = (_Float16)a.z; p[3] = (_Float16)a.w;
    p[4] = (_Float16)b.x; p[5] = (_Float16)b.y; p[6] = (_Float16)b.z; p[7] = (_Float16)b.w;
    ((f16x8*)Wh)[i] = p;
}

// ---------------------------------------------------------------------------
// LayerNorm over D=2048 -> fp16. One block (256 thr) per row, 8 elems/thread.
// Two input variants: fp32 (layer 0 reads x) and fp16 (layers 1-3 read Xh).
// ---------------------------------------------------------------------------
__device__ __forceinline__ void ln_core(float v[8], const float* w,
                                        const float* bln, _Float16* H,
                                        int row, int tid) {
    float s = 0.f, sq = 0.f;
    #pragma unroll
    for (int i = 0; i < 8; i++) { s += v[i]; sq = fmaf(v[i], v[i], sq); }

    #pragma unroll
    for (int off = 32; off > 0; off >>= 1) {
        s  += __shfl_down(s, off);
        sq += __shfl_down(sq, off);
    }

    __shared__ float red[8];
    __shared__ float stats[2];
    const int wv = tid >> 6, ln = tid & 63;
    if (ln == 0) { red[wv] = s; red[4 + wv] = sq; }
    __syncthreads();
    if (tid == 0) {
        float ts = (red[0] + red[1]) + (red[2] + red[3]);
        float tq = (red[4] + red[5]) + (red[6] + red[7]);
        float mean = ts * (1.0f / D_EMBD);
        float var  = tq * (1.0f / D_EMBD) - mean * mean;
        stats[0] = mean;
        stats[1] = rsqrtf(var + 1e-5f);
    }
    __syncthreads();
    const float mean = stats[0], rstd = stats[1];

    float4 w0 = ((const float4*)w)[tid * 2],   w1 = ((const float4*)w)[tid * 2 + 1];
    float4 b0 = ((const float4*)bln)[tid * 2], b1 = ((const float4*)bln)[tid * 2 + 1];
    const float ww[8] = {w0.x, w0.y, w0.z, w0.w, w1.x, w1.y, w1.z, w1.w};
    const float bb[8] = {b0.x, b0.y, b0.z, b0.w, b1.x, b1.y, b1.z, b1.w};

    f16x8 p;
    #pragma unroll
    for (int i = 0; i < 8; i++)
        p[i] = (_Float16)fmaf((v[i] - mean) * rstd, ww[i], bb[i]);
    ((f16x8*)(H + (size_t)row * D_EMBD))[tid] = p;
}

__global__ __launch_bounds__(256) void ln_f32(const float* __restrict__ X,
                                              const float* __restrict__ w,
                                              const float* __restrict__ bln,
                                              _Float16* __restrict__ H) {
    const int row = blockIdx.x, tid = threadIdx.x;
    const float* xr = X + (size_t)row * D_EMBD;
    float4 v0 = ((const float4*)xr)[tid * 2];
    float4 v1 = ((const float4*)xr)[tid * 2 + 1];
    float v[8] = {v0.x, v0.y, v0.z, v0.w, v1.x, v1.y, v1.z, v1.w};
    ln_core(v, w, bln, H, row, tid);
}

__global__ __launch_bounds__(256) void ln_f16(const _Float16* __restrict__ X,
                                              const float* __restrict__ w,
                                              const float* __restrict__ bln,
                                              _Float16* __restrict__ H) {
    const int row = blockIdx.x, tid = threadIdx.x;
    f16x8 h = ((const f16x8*)(X + (size_t)row * D_EMBD))[tid];
    float v[8];
    #pragma unroll
    for (int i = 0; i < 8; i++) v[i] = (float)h[i];
    ln_core(v, w, bln, H, row, tid);
}

// ---------------------------------------------------------------------------
// C[m][n] = gelu( sum_k A[m][k]*B[n][k] + bias[n] )   (B is N x K = W (out,in))
// 128x128 block tile, 4 waves 2x2, each wave 4x4 of 16x16x32 f16 MFMA.
// global_load_lds width-16 staging; XOR-swizzled LDS chunk layout:
//   16B-chunk c of row r stored at chunk position p = c ^ ((r>>1)&3).
// Per ds_read_b128, each 16-lane service group then covers all 8 16B bank
// groups x 2 words (structural minimum) instead of 2 groups x 8 words
// (the measured +4 cyc/read conflict in round 2).
// ---------------------------------------------------------------------------
template <typename OutT>
__global__ __launch_bounds__(256) void gemm_bias_gelu(
    const _Float16* __restrict__ A,   // rows x K fp16 (LN output chunk)
    const _Float16* __restrict__ B,   // N x K fp16 (W layer)
    const float* __restrict__ bias,   // N fp32
    OutT* __restrict__ C)             // rows x N (float or _Float16)
{
    constexpr int K = D_EMBD;
    constexpr int N = D_EMBD;
    __shared__ _Float16 As[TILE * BK];   // 8 KiB
    __shared__ _Float16 Bs[TILE * BK];   // 8 KiB

    const int tid  = threadIdx.x;
    const int m0   = blockIdx.x * TILE;
    const int n0   = blockIdx.y * TILE;
    const int wave = tid >> 6, lane = tid & 63;
    const int wr = wave >> 1, wc = wave & 1;   // 2x2 wave grid, 64x64 each
    const int q = lane >> 4, c16 = lane & 15;

    // Staging: LDS dest e0/e1 are lane-contiguous (wave-uniform base+lane*16);
    // content for dest (row grow, pos tid&3) is global chunk (tid&3)^((grow>>1)&3).
    // Same mask for grow+64 since (grow+64)>>1 == grow>>1 + 32 == grow>>1 mod 4.
    const int grow = tid >> 2;                       // 0..63
    const int gch  = ((tid & 3) ^ ((grow >> 1) & 3)) * 8;
    const int e0 = tid * 8;
    const int e1 = 2048 + tid * 8;

    const _Float16* Ab = A + (size_t)m0 * K;
    const _Float16* Bb = B + (size_t)n0 * K;

    // Fragment read: chunk q of row R lives at pos q ^ ((R>>1)&3);
    // (R>>1)&3 == (c16>>1)&3 because R = (mult of 8 even base) + c16.
    const int rch = (q ^ ((c16 >> 1) & 3)) * 8;

    f32x4 acc[4][4] = {};

    for (int k0 = 0; k0 < K; k0 += BK) {
        async16(Ab + (size_t)grow * K + (k0 + gch), &As[e0]);
        async16(Ab + (size_t)(grow + 64) * K + (k0 + gch), &As[e1]);
        async16(Bb + (size_t)grow * K + (k0 + gch), &Bs[e0]);
        async16(Bb + (size_t)(grow + 64) * K + (k0 + gch), &Bs[e1]);
        __syncthreads();   // drains vmcnt(0): LDS tiles ready

        f16x8 af[4], bf[4];
        #pragma unroll
        for (int i = 0; i < 4; i++)
            af[i] = *(const f16x8*)&As[(wr * 64 + i * 16 + c16) * BK + rch];
        #pragma unroll
        for (int i = 0; i < 4; i++)
            bf[i] = *(const f16x8*)&Bs[(wc * 64 + i * 16 + c16) * BK + rch];

        #pragma unroll
        for (int mi = 0; mi < 4; mi++)
            #pragma unroll
            for (int ni = 0; ni < 4; ni++)
                acc[mi][ni] = __builtin_amdgcn_mfma_f32_16x16x32_f16(
                    af[mi], bf[ni], acc[mi][ni], 0, 0, 0);
        __syncthreads();   // protect LDS before next stage
    }

    // Epilogue: C/D layout col = lane&15, row = q*4 + reg.
    #pragma unroll
    for (int ni = 0; ni < 4; ni++) {
        const int gcol = n0 + wc * 64 + ni * 16 + c16;
        const float bv = bias[gcol];
        #pragma unroll
        for (int mi = 0; mi < 4; mi++) {
            #pragma unroll
            for (int r = 0; r < 4; r++) {
                const int grow2 = m0 + wr * 64 + mi * 16 + q * 4 + r;
                C[(size_t)grow2 * N + gcol] = (OutT)fast_gelu(acc[mi][ni][r] + bv);
            }
        }
    }
}

// ---------------------------------------------------------------------------
extern "C" void kernel_launch(void* const* d_in, const int* in_sizes, int n_in,
                              void* d_out, int out_size, void* d_ws, size_t ws_size,
                              hipStream_t stream) {
    const float* x    = (const float*)d_in[0];   // [8,2048,2048] fp32
    const float* W    = (const float*)d_in[1];   // [4,2048,2048] fp32 (out,in)
    const float* bias = (const float*)d_in[2];   // [4,2048]
    const float* lnw  = (const float*)d_in[3];   // [4,2048]
    const float* lnb  = (const float*)d_in[4];   // [4,2048]
    float* out = (float*)d_out;                  // [8,2048,2048] fp32 (128 MiB)

    // fp16 intermediate activations Xh (16384x2048 fp16 = 64 MiB) live in the
    // TOP HALF of d_out: offset 64 MiB, exactly filling [64,128) MiB.
    // (Round-3 bug: offset 96 MiB overran d_out by 32 MiB -> device fault.)
    // Layer-3 overlap proof: chunks ascend; after chunk ending at row E the
    // fp32 writes cover bytes < 8K*E, while unconsumed Xh rows r >= E start at
    // 64Mi + 4K*r >= 8K*E  (<=> E <= 16384, always true). Within a chunk, the
    // LN kernel (stream-ordered) reads Xh rows into H before the GEMM writes
    // fp32 over them. Layers 0-2 rewrite Xh rows in place (GEMM reads H only).
    _Float16* Xh = (_Float16*)((char*)d_out + (size_t)64 * 1024 * 1024);

    // ws: Wh (one layer fp16, 8 MiB) | H (LN-output fp16, chunked to fit).
    // NEVER exceed ws_size — overrun corrupts the harness's pristine inputs
    // and poisons all subsequent calls (round-1 failure mode).
    const size_t whBytes = (size_t)D_EMBD * D_EMBD * sizeof(_Float16);  // 8 MiB
    _Float16* Wh = (_Float16*)d_ws;
    _Float16* H  = (_Float16*)((char*)d_ws + whBytes);

    const size_t rowBytes = (size_t)D_EMBD * sizeof(_Float16);  // 4 KiB
    long chRows = (ws_size > whBytes) ? (long)((ws_size - whBytes) / rowBytes) : 0;
    chRows = (chRows / TILE) * TILE;
    if (chRows > MROWS) chRows = MROWS;
    if (chRows < TILE)  chRows = TILE;

    for (int layer = 0; layer < 4; layer++) {
        convert_w<<<(D_EMBD * D_EMBD) / 2048, 256, 0, stream>>>(
            W + (size_t)layer * D_EMBD * D_EMBD, Wh);
        for (long m = 0; m < MROWS; m += chRows) {
            const long rows = (MROWS - m < chRows) ? (MROWS - m) : chRows;
            if (layer == 0)
                ln_f32<<<(int)rows, 256, 0, stream>>>(
                    x + (size_t)m * D_EMBD, lnw, lnb, H);
            else
                ln_f16<<<(int)rows, 256, 0, stream>>>(
                    Xh + (size_t)m * D_EMBD, lnw + (size_t)layer * D_EMBD,
                    lnb + (size_t)layer * D_EMBD, H);
            dim3 grid((int)(rows / TILE), D_EMBD / TILE);
            if (layer < 3)
                gemm_bias_gelu<_Float16><<<grid, 256, 0, stream>>>(
                    H, Wh, bias + (size_t)layer * D_EMBD, Xh + (size_t)m * D_EMBD);
            else
                gemm_bias_gelu<float><<<grid, 256, 0, stream>>>(
                    H, Wh, bias + (size_t)layer * D_EMBD, out + (size_t)m * D_EMBD);
        }
    }
}